// Round 2
// baseline (2391.029 us; speedup 1.0000x reference)
//
#include <hip/hip_runtime.h>
#include <cstdint>
#include <cstddef>

#define N_NODES 20000
#define N_EDGES 320000

typedef __attribute__((ext_vector_type(8))) short short8;
typedef __attribute__((ext_vector_type(4))) float floatx4;

__device__ __forceinline__ unsigned short f2bf(float f){
  union { float f; unsigned int i; } v; v.f = f;
  unsigned int u = v.i;
  return (unsigned short)((u + 0x7FFFu + ((u >> 16) & 1u)) >> 16);
}
__device__ __forceinline__ float bf2f(unsigned short u){
  union { unsigned int i; float f; } v; v.i = ((unsigned int)u) << 16; return v.f;
}
__device__ __forceinline__ float siluf(float x){ return x / (1.f + __expf(-x)); }
__device__ __forceinline__ short8 ld_frag16(const unsigned short* p){
  uint4 u = *(const uint4*)p;
  return *(short8*)&u;
}
__device__ __forceinline__ int clampi(int x, int lo, int hi){ return min(max(x, lo), hi); }

// ---------------------------------------------------------------- pack weights (f32 -> bf16 fragments)
__global__ void k_pack(const float* Wq, const float* Wk,
                       const float* Wg1, const float* Wv1,
                       const float* Wg2, const float* Wv2,
                       const float* Wre, const float* Wra,
                       const float* bq, const float* bk,
                       const float* bg1, const float* bv1,
                       const float* bg2, const float* bv2,
                       const float* bre, const float* bra,
                       unsigned short* B1p, unsigned short* Wg2p, unsigned short* Wv2p,
                       unsigned short* Wep,
                       float* bias1, float* biasg2, float* biasv2, float* biase,
                       int* hist)
{
  int tid = blockIdx.x * blockDim.x + threadIdx.x;
  if (tid < 229376){
    int idx, region;
    if (tid < 65536){ region = 0; idx = tid; }
    else if (tid < 114688){ region = 1; idx = tid - 65536; }
    else if (tid < 163840){ region = 2; idx = tid - 114688; }
    else { region = 3; idx = tid - 163840; }
    int j = idx & 7, lane = (idx >> 3) & 63, kk = (idx >> 9) & 3, c = idx >> 11;
    int k = kk*32 + (lane >> 4)*8 + j;
    int n = c*16 + (lane & 15);
    if (region == 0){
      float v = (n < 128) ? Wq[k*128 + n]
              : (n < 256) ? Wk[k*128 + n - 128]
              : (n < 384) ? Wg1[k*128 + n - 256]
              : Wv1[k*128 + n - 384];
      B1p[idx] = f2bf(v);
    } else if (region == 1){ Wg2p[idx] = f2bf(Wg2[k*384 + n]); }
    else if (region == 2){ Wv2p[idx] = f2bf(Wv2[k*384 + n]); }
    else {
      float v = (n < 128) ? Wre[k*128 + n] : Wra[k*384 + n - 128];
      Wep[idx] = f2bf(v);
    }
  }
  if (tid < 512){
    bias1[tid] = tid<128 ? bq[tid] : tid<256 ? bk[tid-128] : tid<384 ? bg1[tid-256] : bv1[tid-384];
    biase[tid] = tid<128 ? bre[tid] : bra[tid-128];
  }
  if (tid < 384){ biasg2[tid] = bg2[tid]; biasv2[tid] = bv2[tid]; }
  if (tid < N_NODES) hist[tid] = 0;
}

// ---------------------------------------------------------------- layernorm (f32 in -> bf16 staging) + v transpose
__global__ void k_ln(const float* s_in, const float* v_in, const float* g, const float* b,
                     unsigned short* s2b, unsigned short* vt)
{
  int wid = threadIdx.x >> 6, lane = threadIdx.x & 63;
  int n = blockIdx.x*4 + wid;
  if (n >= N_NODES) return;
  const float* row = s_in + (size_t)n*128;
  float2 xv = *(const float2*)(row + lane*2);
  float x0 = xv.x, x1 = xv.y;
  float s = x0 + x1, ss = x0*x0 + x1*x1;
  for (int m = 1; m <= 32; m <<= 1){ s += __shfl_xor(s, m); ss += __shfl_xor(ss, m); }
  float mean = s * (1.f/128.f);
  float var = ss * (1.f/128.f) - mean*mean;
  float rs = rsqrtf(var + 1e-5f);
  int ch = lane*2;
  float y0 = (x0-mean)*rs*g[ch]   + b[ch];
  float y1 = (x1-mean)*rs*g[ch+1] + b[ch+1];
  ushort2 ov; ov.x = f2bf(y0); ov.y = f2bf(y1);
  *(ushort2*)(s2b + (size_t)n*128 + ch) = ov;

  // transpose v: vt[node][ch] = {vx, vy, vz, 0} as bf16 (8B per channel)
  float2 va = *(const float2*)(v_in + ((size_t)n*3 + 0)*128 + ch);
  float2 vb = *(const float2*)(v_in + ((size_t)n*3 + 1)*128 + ch);
  float2 vc = *(const float2*)(v_in + ((size_t)n*3 + 2)*128 + ch);
  uint4 wv;
  wv.x = (unsigned int)f2bf(va.x) | ((unsigned int)f2bf(vb.x) << 16);
  wv.y = (unsigned int)f2bf(vc.x);
  wv.z = (unsigned int)f2bf(va.y) | ((unsigned int)f2bf(vb.y) << 16);
  wv.w = (unsigned int)f2bf(vc.y);
  *(uint4*)(vt + (size_t)n*512 + (size_t)ch*4) = wv;
}

// ---------------------------------------------------------------- sort by dst
__global__ void k_hist(const int* ei, int* hist){
  int e = blockIdx.x*blockDim.x + threadIdx.x;
  if (e < N_EDGES){
    int d = clampi(ei[N_EDGES + e], 0, N_NODES-1);
    atomicAdd(&hist[d], 1);
  }
}

__global__ void k_scan(const int* hist, int* row_start, int* cursor){
  __shared__ int wsum[17];
  __shared__ int carry_s;
  int tid = threadIdx.x, lane = tid & 63, wid = tid >> 6;
  if (tid == 0) carry_s = 0;
  __syncthreads();
  for (int base = 0; base < N_NODES; base += 1024){
    int i = base + tid;
    int v = (i < N_NODES) ? hist[i] : 0;
    int incl = v;
    for (int off = 1; off < 64; off <<= 1){
      int t = __shfl_up(incl, off);
      if (lane >= off) incl += t;
    }
    if (lane == 63) wsum[wid] = incl;
    __syncthreads();
    if (tid == 0){
      int acc = carry_s;
      for (int w2 = 0; w2 < 16; w2++){ int t = wsum[w2]; wsum[w2] = acc; acc += t; }
      wsum[16] = acc;
    }
    __syncthreads();
    int excl = wsum[wid] + incl - v;
    if (i < N_NODES){ row_start[i] = excl; cursor[i] = excl; }
    __syncthreads();
    if (tid == 0) carry_s = wsum[16];
    __syncthreads();
  }
  if (threadIdx.x == 0) row_start[N_NODES] = carry_s;
}

__global__ void k_scatter(const int* ei, const float* dir_ij, const float* d_ij,
                          int* cursor, int* perm_s, int* src_s, float* dird_s){
  int e = blockIdx.x*blockDim.x + threadIdx.x;
  if (e < N_EDGES){
    int d = clampi(ei[N_EDGES + e], 0, N_NODES-1);
    int pos = clampi(atomicAdd(&cursor[d], 1), 0, N_EDGES-1);
    perm_s[pos] = e;
    src_s[pos] = clampi(ei[e], 0, N_NODES-1);
    float4 dd;
    dd.x = dir_ij[(size_t)e*3 + 0];
    dd.y = dir_ij[(size_t)e*3 + 1];
    dd.z = dir_ij[(size_t)e*3 + 2];
    dd.w = d_ij[e];
    *(float4*)(dird_s + (size_t)pos*4) = dd;
  }
}

// ---------------------------------------------------------------- node GEMM 1: [q|k|silu(g1)|silu(v1)]
__global__ void __launch_bounds__(256) k_ngemm1(const unsigned short* s2b, const unsigned short* B1p, const float* bias1,
                        unsigned short* q_b, unsigned short* k_b, unsigned short* h1_b, unsigned short* h2_b)
{
  int wid = threadIdx.x >> 6, lane = threadIdx.x & 63;
  int tile = blockIdx.x*4 + wid;
  if (tile >= N_NODES/16) return;
  int l15 = lane & 15, q = lane >> 4;
  int n0 = tile*16;
  const unsigned short* arow = s2b + (size_t)(n0 + l15)*128 + q*8;
  short8 af[4];
  for (int kk = 0; kk < 4; kk++) af[kk] = ld_frag16(arow + kk*32);
  for (int c = 0; c < 32; c++){
    floatx4 acc = {0.f,0.f,0.f,0.f};
    const unsigned short* bp = B1p + (size_t)(c*4)*512 + lane*8;
    for (int kk = 0; kk < 4; kk++){
      short8 bf = ld_frag16(bp + kk*512);
      acc = __builtin_amdgcn_mfma_f32_16x16x32_bf16(af[kk], bf, acc, 0, 0, 0);
    }
    int col = c*16 + l15;
    float bias = bias1[col];
    unsigned short* dst; int cc;
    if      (c < 8){  dst = q_b;  cc = col; }
    else if (c < 16){ dst = k_b;  cc = col - 128; }
    else if (c < 24){ dst = h1_b; cc = col - 256; }
    else            { dst = h2_b; cc = col - 384; }
    bool act = (c >= 16);
    for (int r = 0; r < 4; r++){
      float vv = acc[r] + bias;
      if (act) vv = siluf(vv);
      int node = n0 + q*4 + r;
      dst[(size_t)node*128 + cc] = f2bf(vv);
    }
  }
}

// ---------------------------------------------------------------- node GEMM 2: x3 / val interleaved into xv
__global__ void __launch_bounds__(256) k_ngemm2(const unsigned short* h1_b, const unsigned short* h2_b,
                        const unsigned short* Wg2p, const unsigned short* Wv2p,
                        const float* biasg2, const float* biasv2,
                        unsigned short* xv_b)
{
  int wid = threadIdx.x >> 6, lane = threadIdx.x & 63;
  int tile = blockIdx.x*4 + wid;
  if (tile >= N_NODES/16) return;
  int l15 = lane & 15, q = lane >> 4;
  int n0 = tile*16;
  for (int ph = 0; ph < 2; ph++){
    const unsigned short* srcm = ph ? h2_b : h1_b;
    const unsigned short* Wp   = ph ? Wv2p : Wg2p;
    const float* bs            = ph ? biasv2 : biasg2;
    const unsigned short* arow = srcm + (size_t)(n0 + l15)*128 + q*8;
    short8 af[4];
    for (int kk = 0; kk < 4; kk++) af[kk] = ld_frag16(arow + kk*32);
    for (int c = 0; c < 24; c++){
      floatx4 acc = {0.f,0.f,0.f,0.f};
      const unsigned short* bp = Wp + (size_t)(c*4)*512 + lane*8;
      for (int kk = 0; kk < 4; kk++){
        short8 bf = ld_frag16(bp + kk*512);
        acc = __builtin_amdgcn_mfma_f32_16x16x32_bf16(af[kk], bf, acc, 0, 0, 0);
      }
      int col = c*16 + l15;
      float bias = bs[col];
      for (int r = 0; r < 4; r++){
        float vv = acc[r] + bias;
        int node = n0 + q*4 + r;
        xv_b[(((size_t)node*384 + col) << 1) + ph] = f2bf(vv);
      }
    }
  }
}

// ---------------------------------------------------------------- pass B: alpha logits + online softmax stats + r_ij copy-out
__global__ void __launch_bounds__(256) k_alpha(const float* r_ij, const unsigned short* q_b, const unsigned short* k_b,
                       const unsigned short* Wep, const float* biase,
                       const int* row_start, const int* perm_s, const int* src_s,
                       float* alpha_s, float* stats_s, float* r_out)
{
  int wid = threadIdx.x >> 6, lane = threadIdx.x & 63;
  int n = blockIdx.x*4 + wid;
  int l15 = lane & 15, q = lane >> 4;
  int rs = clampi(row_start[n], 0, N_EDGES);
  int re = clampi(row_start[n+1], rs, N_EDGES);
  if (re <= rs) return;

  // online per-head softmax stats, kept in registers (all 16 lanes of a
  // group hold identical reduced logits after the butterfly, so updates
  // are redundantly uniform within the group; groups merged at the end).
  float m_run[8], z_run[8];
  #pragma unroll
  for (int h = 0; h < 8; h++){ m_run[h] = -1e30f; z_run[h] = 0.f; }

  for (int c0 = rs; c0 < re; c0 += 16){
    int iA = min(c0 + l15, re-1);
    bool validA = (c0 + l15 < re);
    int pA = clampi(perm_s[iA], 0, N_EDGES-1);
    const float* ar = r_ij + (size_t)pA*128 + q*8;
    float*       wr = r_out + (size_t)pA*128 + q*8;
    short8 af[4];
    for (int kk = 0; kk < 4; kk++){
      float4 a0 = *(const float4*)(ar + kk*32);
      float4 a1 = *(const float4*)(ar + kk*32 + 4);
      if (validA){ *(float4*)(wr + kk*32) = a0; *(float4*)(wr + kk*32 + 4) = a1; }
      short8 f;
      f[0]=(short)f2bf(a0.x); f[1]=(short)f2bf(a0.y); f[2]=(short)f2bf(a0.z); f[3]=(short)f2bf(a0.w);
      f[4]=(short)f2bf(a1.x); f[5]=(short)f2bf(a1.y); f[6]=(short)f2bf(a1.z); f[7]=(short)f2bf(a1.w);
      af[kk] = f;
    }
    int sv[4]; int er_[4]; bool vr[4];
    for (int r = 0; r < 4; r++){
      int e = c0 + q*4 + r;
      vr[r] = (e < re);
      int ec = min(e, re-1);
      er_[r] = e;
      sv[r] = clampi(src_s[ec], 0, N_NODES-1);
    }
    #pragma unroll
    for (int c = 0; c < 8; c++){
      floatx4 acc = {0.f,0.f,0.f,0.f};
      const unsigned short* bp = Wep + (size_t)(c*4)*512 + lane*8;
      #pragma unroll
      for (int kk = 0; kk < 4; kk++){
        short8 bf = ld_frag16(bp + kk*512);
        acc = __builtin_amdgcn_mfma_f32_16x16x32_bf16(af[kk], bf, acc, 0, 0, 0);
      }
      float bias = biase[c*16 + l15];
      float qv = bf2f(q_b[(size_t)n*128 + c*16 + l15]);
      float t0[4];
      #pragma unroll
      for (int r = 0; r < 4; r++){
        float kvv = bf2f(k_b[(size_t)sv[r]*128 + c*16 + l15]);
        t0[r] = siluf(acc[r] + bias) * qv * kvv;
      }
      for (int m = 1; m <= 8; m <<= 1)
        #pragma unroll
        for (int r = 0; r < 4; r++) t0[r] += __shfl_xor(t0[r], m);
      if (l15 == 0){
        #pragma unroll
        for (int r = 0; r < 4; r++)
          if (vr[r]) alpha_s[(size_t)er_[r]*8 + c] = t0[r];
      }
      #pragma unroll
      for (int r = 0; r < 4; r++){
        if (vr[r]){
          float t = t0[r];
          float mn = fmaxf(m_run[c], t);
          z_run[c] = z_run[c]*__expf(m_run[c]-mn) + __expf(t-mn);
          m_run[c] = mn;
        }
      }
    }
  }
  // merge stats across the 4 lane-groups (butterfly leaves full result on all lanes)
  #pragma unroll
  for (int h = 0; h < 8; h++){
    float mo = m_run[h], zo = z_run[h];
    for (int m = 16; m <= 32; m <<= 1){
      float m2 = __shfl_xor(mo, m), z2 = __shfl_xor(zo, m);
      float mn = fmaxf(mo, m2);
      zo = zo*__expf(mo-mn) + z2*__expf(m2-mn);
      mo = mn;
    }
    m_run[h] = mo; z_run[h] = zo;
  }
  if (lane == 0){
    #pragma unroll
    for (int h = 0; h < 8; h++){
      stats_s[(size_t)n*16 + h]     = m_run[h];
      stats_s[(size_t)n*16 + 8 + h] = 1.f / (z_run[h] + 1e-16f);
    }
  }
}

// ---------------------------------------------------------------- pass C: messages + fused node reduction
__global__ void __launch_bounds__(256) k_msg(const float* s_in, const float* v_in,
                     const float* r_ij,
                     const float* ln_g, const float* ln_b,
                     const unsigned short* xv_b, const unsigned short* vt_b,
                     const unsigned short* Wep, const float* biase,
                     const int* row_start, const int* perm_s, const int* src_s,
                     const float* dird_s, const float* alpha_s, const float* stats_s,
                     float* out_s, float* out_v)
{
  int wid = threadIdx.x >> 6, lane = threadIdx.x & 63;
  int n = blockIdx.x*4 + wid;
  int l15 = lane & 15, q = lane >> 4;
  int rs = clampi(row_start[n], 0, N_EDGES);
  int re = clampi(row_start[n+1], rs, N_EDGES);

  float accS[2] = {0.f, 0.f};
  float accV[6] = {0.f,0.f,0.f,0.f,0.f,0.f};

  // per-node softmax stats (written by k_alpha; garbage-but-unused for empty rows)
  float4 st0 = *(const float4*)(stats_s + (size_t)n*16);
  float4 st1 = *(const float4*)(stats_s + (size_t)n*16 + 4);
  float4 st2 = *(const float4*)(stats_s + (size_t)n*16 + 8);
  float4 st3 = *(const float4*)(stats_s + (size_t)n*16 + 12);
  float mh_[8] = {st0.x,st0.y,st0.z,st0.w,st1.x,st1.y,st1.z,st1.w};
  float zi_[8] = {st2.x,st2.y,st2.z,st2.w,st3.x,st3.y,st3.z,st3.w};

  for (int c0 = rs; c0 < re; c0 += 16){
    int iA = min(c0 + l15, re-1);
    int pA = clampi(perm_s[iA], 0, N_EDGES-1);
    const float* ar = r_ij + (size_t)pA*128 + q*8;
    short8 af[4];
    #pragma unroll
    for (int kk = 0; kk < 4; kk++){
      float4 a0 = *(const float4*)(ar + kk*32);
      float4 a1 = *(const float4*)(ar + kk*32 + 4);
      short8 f;
      f[0]=(short)f2bf(a0.x); f[1]=(short)f2bf(a0.y); f[2]=(short)f2bf(a0.z); f[3]=(short)f2bf(a0.w);
      f[4]=(short)f2bf(a1.x); f[5]=(short)f2bf(a1.y); f[6]=(short)f2bf(a1.z); f[7]=(short)f2bf(a1.w);
      af[kk] = f;
    }

    // per-edge metadata + attention weights, batched up-front (wide loads)
    int sv[4]; float cc[4], dv0[4], dv1[4], dv2[4];
    float ath[4][8];
    #pragma unroll
    for (int r = 0; r < 4; r++){
      int e = c0 + q*4 + r;
      bool vrr = (e < re);
      int ec = min(e, re-1);
      sv[r] = clampi(src_s[ec], 0, N_NODES-1);
      float4 dd = *(const float4*)(dird_s + (size_t)ec*4);
      cc[r] = (vrr && dd.w < 5.0f) ? 0.5f*(__cosf(dd.w*0.6283185307179587f) + 1.f) : 0.f;
      dv0[r] = dd.x; dv1[r] = dd.y; dv2[r] = dd.z;
      float4 A0 = *(const float4*)(alpha_s + (size_t)ec*8);
      float4 A1 = *(const float4*)(alpha_s + (size_t)ec*8 + 4);
      float sc = vrr ? 1.f : 0.f;
      ath[r][0] = __expf(A0.x - mh_[0]) * zi_[0] * sc;
      ath[r][1] = __expf(A0.y - mh_[1]) * zi_[1] * sc;
      ath[r][2] = __expf(A0.z - mh_[2]) * zi_[2] * sc;
      ath[r][3] = __expf(A0.w - mh_[3]) * zi_[3] * sc;
      ath[r][4] = __expf(A1.x - mh_[4]) * zi_[4] * sc;
      ath[r][5] = __expf(A1.y - mh_[5]) * zi_[5] * sc;
      ath[r][6] = __expf(A1.z - mh_[6]) * zi_[6] * sc;
      ath[r][7] = __expf(A1.w - mh_[7]) * zi_[7] * sc;
    }

    #pragma unroll
    for (int c = 0; c < 24; c++){
      const int h = c / 3;   // compile-time under full unroll
      floatx4 acc = {0.f,0.f,0.f,0.f};
      const unsigned short* bp = Wep + (size_t)((8+c)*4)*512 + lane*8;
      #pragma unroll
      for (int kk = 0; kk < 4; kk++){
        short8 bf = ld_frag16(bp + kk*512);
        acc = __builtin_amdgcn_mfma_f32_16x16x32_bf16(af[kk], bf, acc, 0, 0, 0);
      }
      float bias = biase[128 + c*16 + l15];
      float msg[4];
      #pragma unroll
      for (int r = 0; r < 4; r++){
        unsigned int xv = *(const unsigned int*)(xv_b + (((size_t)sv[r]*384 + c*16 + l15) << 1));
        float xvf = bf2f((unsigned short)(xv & 0xffffu));
        float vvf = bf2f((unsigned short)(xv >> 16));
        msg[r] = (acc[r] + bias) * xvf * cc[r] + ath[r][h] * vvf;
      }
      if (c < 8){
        float s4 = msg[0]+msg[1]+msg[2]+msg[3];
        s4 += __shfl_xor(s4, 16); s4 += __shfl_xor(s4, 32);
        if (q == (c & 3)) accS[c >> 2] += s4;
      } else if (c < 16){
        int b = c - 8;
        float p0 = msg[0]*dv0[0] + msg[1]*dv0[1] + msg[2]*dv0[2] + msg[3]*dv0[3];
        float p1 = msg[0]*dv1[0] + msg[1]*dv1[1] + msg[2]*dv1[2] + msg[3]*dv1[3];
        float p2 = msg[0]*dv2[0] + msg[1]*dv2[1] + msg[2]*dv2[2] + msg[3]*dv2[3];
        p0 += __shfl_xor(p0, 16); p0 += __shfl_xor(p0, 32);
        p1 += __shfl_xor(p1, 16); p1 += __shfl_xor(p1, 32);
        p2 += __shfl_xor(p2, 16); p2 += __shfl_xor(p2, 32);
        if (q == (b & 3)){
          accV[(b >> 2)*3 + 0] += p0;
          accV[(b >> 2)*3 + 1] += p1;
          accV[(b >> 2)*3 + 2] += p2;
        }
      } else {
        int b = c - 16;
        float p0 = 0.f, p1 = 0.f, p2 = 0.f;
        #pragma unroll
        for (int r = 0; r < 4; r++){
          uint2 vv = *(const uint2*)(vt_b + (((size_t)sv[r]*128 + b*16 + l15) << 2));
          p0 += msg[r] * bf2f((unsigned short)(vv.x & 0xffffu));
          p1 += msg[r] * bf2f((unsigned short)(vv.x >> 16));
          p2 += msg[r] * bf2f((unsigned short)(vv.y & 0xffffu));
        }
        p0 += __shfl_xor(p0, 16); p0 += __shfl_xor(p0, 32);
        p1 += __shfl_xor(p1, 16); p1 += __shfl_xor(p1, 32);
        p2 += __shfl_xor(p2, 16); p2 += __shfl_xor(p2, 32);
        if (q == (b & 3)){
          accV[(b >> 2)*3 + 0] += p0;
          accV[(b >> 2)*3 + 1] += p1;
          accV[(b >> 2)*3 + 2] += p2;
        }
      }
    }
  }

  // epilogue: recompute LN(s) in f32 and fuse s_out = LN(s) + su ; v_out = v + vu
  {
    int ch0 = q*16 + l15, ch1 = 64 + q*16 + l15;
    float x0 = s_in[(size_t)n*128 + ch0];
    float x1 = s_in[(size_t)n*128 + ch1];
    float sm = x0 + x1, ssq = x0*x0 + x1*x1;
    for (int m = 1; m <= 32; m <<= 1){ sm += __shfl_xor(sm, m); ssq += __shfl_xor(ssq, m); }
    float mean = sm * (1.f/128.f);
    float var = ssq * (1.f/128.f) - mean*mean;
    float rsv = rsqrtf(var + 1e-5f);
    float y0 = (x0-mean)*rsv*ln_g[ch0] + ln_b[ch0];
    float y1 = (x1-mean)*rsv*ln_g[ch1] + ln_b[ch1];
    out_s[(size_t)n*128 + ch0] = y0 + accS[0];
    out_s[(size_t)n*128 + ch1] = y1 + accS[1];
  }
  for (int t = 0; t < 6; t++){
    int b = (t/3)*4 + q;
    int a = t - (t/3)*3;
    int ch = b*16 + l15;
    size_t idx = ((size_t)n*3 + a)*128 + ch;
    out_v[idx] = v_in[idx] + accV[t];
  }
}

// ---------------------------------------------------------------- launch
extern "C" void kernel_launch(void* const* d_in, const int* in_sizes, int n_in,
                              void* d_out, int out_size, void* d_ws, size_t ws_size,
                              hipStream_t stream)
{
  const float* s_in   = (const float*)d_in[0];
  const float* v_in   = (const float*)d_in[1];
  const float* dir_ij = (const float*)d_in[2];
  const float* d_ij   = (const float*)d_in[3];
  const float* r_ij   = (const float*)d_in[4];
  const int*   ei     = (const int*)d_in[5];
  const float* ln_g   = (const float*)d_in[6];
  const float* ln_b   = (const float*)d_in[7];
  const float* Wq  = (const float*)d_in[8];
  const float* bq  = (const float*)d_in[9];
  const float* Wk  = (const float*)d_in[10];
  const float* bk  = (const float*)d_in[11];
  const float* Wg1 = (const float*)d_in[12];
  const float* bg1 = (const float*)d_in[13];
  const float* Wg2 = (const float*)d_in[14];
  const float* bg2 = (const float*)d_in[15];
  const float* Wv1 = (const float*)d_in[16];
  const float* bv1 = (const float*)d_in[17];
  const float* Wv2 = (const float*)d_in[18];
  const float* bv2 = (const float*)d_in[19];
  const float* Wre = (const float*)d_in[20];
  const float* bre = (const float*)d_in[21];
  const float* Wra = (const float*)d_in[22];
  const float* bra = (const float*)d_in[23];

  float* out_s = (float*)d_out;
  float* out_v = out_s + (size_t)N_NODES*128;
  float* out_r = out_v + (size_t)N_NODES*384;

  char* w = (char*)d_ws;
  size_t off = 0;
  auto alloc = [&](size_t bytes) -> void* {
    void* p = w + off;
    off = (off + bytes + 255) & ~(size_t)255;
    return p;
  };
  // region 0: h1|h2 during ngemm1/2, then alpha_s (same 10.24 MB)
  char* reg0 = (char*)alloc((size_t)N_EDGES*8*4);
  unsigned short* h1_b  = (unsigned short*)reg0;
  unsigned short* h2_b  = (unsigned short*)(reg0 + (size_t)N_NODES*128*2);
  float* alpha_s        = (float*)reg0;
  // region 1: xv (x3|val interleaved); its first 5.12 MB doubles as s2b before ngemm2
  unsigned short* xv_b  = (unsigned short*)alloc((size_t)N_NODES*384*2*2);
  unsigned short* s2b   = xv_b;
  unsigned short* q_b   = (unsigned short*)alloc((size_t)N_NODES*128*2);
  unsigned short* k_b   = (unsigned short*)alloc((size_t)N_NODES*128*2);
  unsigned short* vt_b  = (unsigned short*)alloc((size_t)N_NODES*128*4*2);
  float* dird_s  = (float*)alloc((size_t)N_EDGES*4*4);
  float* stats_s = (float*)alloc((size_t)N_NODES*16*4);
  unsigned short* B1p   = (unsigned short*)alloc(65536*2);
  unsigned short* Wg2p  = (unsigned short*)alloc(49152*2);
  unsigned short* Wv2p  = (unsigned short*)alloc(49152*2);
  unsigned short* Wep   = (unsigned short*)alloc(65536*2);
  float* bias1  = (float*)alloc(512*4);
  float* biasg2 = (float*)alloc(384*4);
  float* biasv2 = (float*)alloc(384*4);
  float* biase  = (float*)alloc(512*4);
  int* hist      = (int*)alloc((size_t)N_NODES*4);
  int* row_start = (int*)alloc((size_t)(N_NODES+1)*4);
  int* cursor    = (int*)alloc((size_t)N_NODES*4);
  int* perm_s    = (int*)alloc((size_t)N_EDGES*4);
  int* src_s     = (int*)alloc((size_t)N_EDGES*4);

  k_pack<<<896, 256, 0, stream>>>(Wq, Wk, Wg1, Wv1, Wg2, Wv2, Wre, Wra,
                                  bq, bk, bg1, bv1, bg2, bv2, bre, bra,
                                  B1p, Wg2p, Wv2p, Wep,
                                  bias1, biasg2, biasv2, biase, hist);
  k_ln<<<5000, 256, 0, stream>>>(s_in, v_in, ln_g, ln_b, s2b, vt_b);
  k_hist<<<1250, 256, 0, stream>>>(ei, hist);
  k_scan<<<1, 1024, 0, stream>>>(hist, row_start, cursor);
  k_scatter<<<1250, 256, 0, stream>>>(ei, dir_ij, d_ij, cursor, perm_s, src_s, dird_s);
  k_ngemm1<<<313, 256, 0, stream>>>(s2b, B1p, bias1, q_b, k_b, h1_b, h2_b);
  k_ngemm2<<<313, 256, 0, stream>>>(h1_b, h2_b, Wg2p, Wv2p, biasg2, biasv2, xv_b);
  k_alpha<<<5000, 256, 0, stream>>>(r_ij, q_b, k_b, Wep, biase, row_start, perm_s, src_s,
                                    alpha_s, stats_s, out_r);
  k_msg<<<5000, 256, 0, stream>>>(s_in, v_in, r_ij, ln_g, ln_b,
                                  xv_b, vt_b, Wep, biase,
                                  row_start, perm_s, src_s, dird_s, alpha_s, stats_s,
                                  out_s, out_v);
}

// Round 3
// 1020.843 us; speedup vs baseline: 2.3422x; 2.3422x over previous
//
#include <hip/hip_runtime.h>
#include <cstdint>
#include <cstddef>

#define N_NODES 20000
#define N_EDGES 320000

typedef __attribute__((ext_vector_type(8))) short short8;
typedef __attribute__((ext_vector_type(4))) float floatx4;

__device__ __forceinline__ unsigned short f2bf(float f){
  union { float f; unsigned int i; } v; v.f = f;
  unsigned int u = v.i;
  return (unsigned short)((u + 0x7FFFu + ((u >> 16) & 1u)) >> 16);
}
__device__ __forceinline__ float bf2f(unsigned short u){
  union { unsigned int i; float f; } v; v.i = ((unsigned int)u) << 16; return v.f;
}
__device__ __forceinline__ float siluf(float x){ return x / (1.f + __expf(-x)); }
__device__ __forceinline__ short8 ld_frag16(const unsigned short* p){
  uint4 u = *(const uint4*)p;
  return *(short8*)&u;
}
__device__ __forceinline__ int clampi(int x, int lo, int hi){ return min(max(x, lo), hi); }

// ---------------------------------------------------------------- pack weights (f32 -> bf16 fragments)
__global__ void k_pack(const float* Wq, const float* Wk,
                       const float* Wg1, const float* Wv1,
                       const float* Wg2, const float* Wv2,
                       const float* Wre, const float* Wra,
                       const float* bq, const float* bk,
                       const float* bg1, const float* bv1,
                       const float* bg2, const float* bv2,
                       const float* bre, const float* bra,
                       unsigned short* B1p, unsigned short* Wg2p, unsigned short* Wv2p,
                       unsigned short* Wep,
                       float* bias1, float* biasg2, float* biasv2, float* biase,
                       int* hist)
{
  int tid = blockIdx.x * blockDim.x + threadIdx.x;
  if (tid < 229376){
    int idx, region;
    if (tid < 65536){ region = 0; idx = tid; }
    else if (tid < 114688){ region = 1; idx = tid - 65536; }
    else if (tid < 163840){ region = 2; idx = tid - 114688; }
    else { region = 3; idx = tid - 163840; }
    int j = idx & 7, lane = (idx >> 3) & 63, kk = (idx >> 9) & 3, c = idx >> 11;
    int k = kk*32 + (lane >> 4)*8 + j;
    int n = c*16 + (lane & 15);
    if (region == 0){
      float v = (n < 128) ? Wq[k*128 + n]
              : (n < 256) ? Wk[k*128 + n - 128]
              : (n < 384) ? Wg1[k*128 + n - 256]
              : Wv1[k*128 + n - 384];
      B1p[idx] = f2bf(v);
    } else if (region == 1){ Wg2p[idx] = f2bf(Wg2[k*384 + n]); }
    else if (region == 2){ Wv2p[idx] = f2bf(Wv2[k*384 + n]); }
    else {
      float v = (n < 128) ? Wre[k*128 + n] : Wra[k*384 + n - 128];
      Wep[idx] = f2bf(v);
    }
  }
  if (tid < 512){
    bias1[tid] = tid<128 ? bq[tid] : tid<256 ? bk[tid-128] : tid<384 ? bg1[tid-256] : bv1[tid-384];
    biase[tid] = tid<128 ? bre[tid] : bra[tid-128];
  }
  if (tid < 384){ biasg2[tid] = bg2[tid]; biasv2[tid] = bv2[tid]; }
  if (tid < N_NODES) hist[tid] = 0;
}

// ---------------------------------------------------------------- layernorm (f32 in -> bf16 staging) + v transpose
__global__ void k_ln(const float* s_in, const float* v_in, const float* g, const float* b,
                     unsigned short* s2b, unsigned short* vt)
{
  int wid = threadIdx.x >> 6, lane = threadIdx.x & 63;
  int n = blockIdx.x*4 + wid;
  if (n >= N_NODES) return;
  const float* row = s_in + (size_t)n*128;
  float2 xv = *(const float2*)(row + lane*2);
  float x0 = xv.x, x1 = xv.y;
  float s = x0 + x1, ss = x0*x0 + x1*x1;
  for (int m = 1; m <= 32; m <<= 1){ s += __shfl_xor(s, m); ss += __shfl_xor(ss, m); }
  float mean = s * (1.f/128.f);
  float var = ss * (1.f/128.f) - mean*mean;
  float rs = rsqrtf(var + 1e-5f);
  int ch = lane*2;
  float y0 = (x0-mean)*rs*g[ch]   + b[ch];
  float y1 = (x1-mean)*rs*g[ch+1] + b[ch+1];
  ushort2 ov; ov.x = f2bf(y0); ov.y = f2bf(y1);
  *(ushort2*)(s2b + (size_t)n*128 + ch) = ov;

  // transpose v: vt[node][ch] = {vx, vy, vz, 0} as bf16 (8B per channel)
  float2 va = *(const float2*)(v_in + ((size_t)n*3 + 0)*128 + ch);
  float2 vb = *(const float2*)(v_in + ((size_t)n*3 + 1)*128 + ch);
  float2 vc = *(const float2*)(v_in + ((size_t)n*3 + 2)*128 + ch);
  uint4 wv;
  wv.x = (unsigned int)f2bf(va.x) | ((unsigned int)f2bf(vb.x) << 16);
  wv.y = (unsigned int)f2bf(vc.x);
  wv.z = (unsigned int)f2bf(va.y) | ((unsigned int)f2bf(vb.y) << 16);
  wv.w = (unsigned int)f2bf(vc.y);
  *(uint4*)(vt + (size_t)n*512 + (size_t)ch*4) = wv;
}

// ---------------------------------------------------------------- sort by dst
__global__ void k_hist(const int* ei, int* hist){
  int e = blockIdx.x*blockDim.x + threadIdx.x;
  if (e < N_EDGES){
    int d = clampi(ei[N_EDGES + e], 0, N_NODES-1);
    atomicAdd(&hist[d], 1);
  }
}

__global__ void k_scan(const int* hist, int* row_start, int* cursor){
  __shared__ int wsum[17];
  __shared__ int carry_s;
  int tid = threadIdx.x, lane = tid & 63, wid = tid >> 6;
  if (tid == 0) carry_s = 0;
  __syncthreads();
  for (int base = 0; base < N_NODES; base += 1024){
    int i = base + tid;
    int v = (i < N_NODES) ? hist[i] : 0;
    int incl = v;
    for (int off = 1; off < 64; off <<= 1){
      int t = __shfl_up(incl, off);
      if (lane >= off) incl += t;
    }
    if (lane == 63) wsum[wid] = incl;
    __syncthreads();
    if (tid == 0){
      int acc = carry_s;
      for (int w2 = 0; w2 < 16; w2++){ int t = wsum[w2]; wsum[w2] = acc; acc += t; }
      wsum[16] = acc;
    }
    __syncthreads();
    int excl = wsum[wid] + incl - v;
    if (i < N_NODES){ row_start[i] = excl; cursor[i] = excl; }
    __syncthreads();
    if (tid == 0) carry_s = wsum[16];
    __syncthreads();
  }
  if (threadIdx.x == 0) row_start[N_NODES] = carry_s;
}

__global__ void k_scatter(const int* ei, const float* dir_ij, const float* d_ij,
                          int* cursor, int* perm_s, int* src_s, float* dird_s){
  int e = blockIdx.x*blockDim.x + threadIdx.x;
  if (e < N_EDGES){
    int d = clampi(ei[N_EDGES + e], 0, N_NODES-1);
    int pos = clampi(atomicAdd(&cursor[d], 1), 0, N_EDGES-1);
    perm_s[pos] = e;
    src_s[pos] = clampi(ei[e], 0, N_NODES-1);
    float4 dd;
    dd.x = dir_ij[(size_t)e*3 + 0];
    dd.y = dir_ij[(size_t)e*3 + 1];
    dd.z = dir_ij[(size_t)e*3 + 2];
    dd.w = d_ij[e];
    *(float4*)(dird_s + (size_t)pos*4) = dd;
  }
}

// ---------------------------------------------------------------- node GEMM 1: [q|k|silu(g1)|silu(v1)]
__global__ void __launch_bounds__(256) k_ngemm1(const unsigned short* s2b, const unsigned short* B1p, const float* bias1,
                        unsigned short* q_b, unsigned short* k_b, unsigned short* h1_b, unsigned short* h2_b)
{
  int wid = threadIdx.x >> 6, lane = threadIdx.x & 63;
  int tile = blockIdx.x*4 + wid;
  if (tile >= N_NODES/16) return;
  int l15 = lane & 15, q = lane >> 4;
  int n0 = tile*16;
  const unsigned short* arow = s2b + (size_t)(n0 + l15)*128 + q*8;
  short8 af[4];
  for (int kk = 0; kk < 4; kk++) af[kk] = ld_frag16(arow + kk*32);
  for (int c = 0; c < 32; c++){
    floatx4 acc = {0.f,0.f,0.f,0.f};
    const unsigned short* bp = B1p + (size_t)(c*4)*512 + lane*8;
    for (int kk = 0; kk < 4; kk++){
      short8 bf = ld_frag16(bp + kk*512);
      acc = __builtin_amdgcn_mfma_f32_16x16x32_bf16(af[kk], bf, acc, 0, 0, 0);
    }
    int col = c*16 + l15;
    float bias = bias1[col];
    unsigned short* dst; int cc;
    if      (c < 8){  dst = q_b;  cc = col; }
    else if (c < 16){ dst = k_b;  cc = col - 128; }
    else if (c < 24){ dst = h1_b; cc = col - 256; }
    else            { dst = h2_b; cc = col - 384; }
    bool act = (c >= 16);
    for (int r = 0; r < 4; r++){
      float vv = acc[r] + bias;
      if (act) vv = siluf(vv);
      int node = n0 + q*4 + r;
      dst[(size_t)node*128 + cc] = f2bf(vv);
    }
  }
}

// ---------------------------------------------------------------- node GEMM 2: x3 / val interleaved into xv
__global__ void __launch_bounds__(256) k_ngemm2(const unsigned short* h1_b, const unsigned short* h2_b,
                        const unsigned short* Wg2p, const unsigned short* Wv2p,
                        const float* biasg2, const float* biasv2,
                        unsigned short* xv_b)
{
  int wid = threadIdx.x >> 6, lane = threadIdx.x & 63;
  int tile = blockIdx.x*4 + wid;
  if (tile >= N_NODES/16) return;
  int l15 = lane & 15, q = lane >> 4;
  int n0 = tile*16;
  for (int ph = 0; ph < 2; ph++){
    const unsigned short* srcm = ph ? h2_b : h1_b;
    const unsigned short* Wp   = ph ? Wv2p : Wg2p;
    const float* bs            = ph ? biasv2 : biasg2;
    const unsigned short* arow = srcm + (size_t)(n0 + l15)*128 + q*8;
    short8 af[4];
    for (int kk = 0; kk < 4; kk++) af[kk] = ld_frag16(arow + kk*32);
    for (int c = 0; c < 24; c++){
      floatx4 acc = {0.f,0.f,0.f,0.f};
      const unsigned short* bp = Wp + (size_t)(c*4)*512 + lane*8;
      for (int kk = 0; kk < 4; kk++){
        short8 bf = ld_frag16(bp + kk*512);
        acc = __builtin_amdgcn_mfma_f32_16x16x32_bf16(af[kk], bf, acc, 0, 0, 0);
      }
      int col = c*16 + l15;
      float bias = bs[col];
      for (int r = 0; r < 4; r++){
        float vv = acc[r] + bias;
        int node = n0 + q*4 + r;
        xv_b[(((size_t)node*384 + col) << 1) + ph] = f2bf(vv);
      }
    }
  }
}

// ---------------------------------------------------------------- pass B: alpha logits + online softmax stats + r_ij copy-out
__global__ void __launch_bounds__(256) k_alpha(const float* r_ij, const unsigned short* q_b, const unsigned short* k_b,
                       const unsigned short* Wep, const float* biase,
                       const int* row_start, const int* perm_s, const int* src_s,
                       float* alpha_s, float* stats_s, float* r_out)
{
  int wid = threadIdx.x >> 6, lane = threadIdx.x & 63;
  int n = blockIdx.x*4 + wid;
  int l15 = lane & 15, q = lane >> 4;
  int rs = clampi(row_start[n], 0, N_EDGES);
  int re = clampi(row_start[n+1], rs, N_EDGES);
  if (re <= rs) return;

  // online per-head softmax stats, kept in registers (all 16 lanes of a
  // group hold identical reduced logits after the butterfly, so updates
  // are redundantly uniform within the group; groups merged at the end).
  float m_run[8], z_run[8];
  #pragma unroll
  for (int h = 0; h < 8; h++){ m_run[h] = -1e30f; z_run[h] = 0.f; }

  for (int c0 = rs; c0 < re; c0 += 16){
    int iA = min(c0 + l15, re-1);
    bool validA = (c0 + l15 < re);
    int pA = clampi(perm_s[iA], 0, N_EDGES-1);
    const float* ar = r_ij + (size_t)pA*128 + q*8;
    float*       wr = r_out + (size_t)pA*128 + q*8;
    short8 af[4];
    for (int kk = 0; kk < 4; kk++){
      float4 a0 = *(const float4*)(ar + kk*32);
      float4 a1 = *(const float4*)(ar + kk*32 + 4);
      if (validA){ *(float4*)(wr + kk*32) = a0; *(float4*)(wr + kk*32 + 4) = a1; }
      short8 f;
      f[0]=(short)f2bf(a0.x); f[1]=(short)f2bf(a0.y); f[2]=(short)f2bf(a0.z); f[3]=(short)f2bf(a0.w);
      f[4]=(short)f2bf(a1.x); f[5]=(short)f2bf(a1.y); f[6]=(short)f2bf(a1.z); f[7]=(short)f2bf(a1.w);
      af[kk] = f;
    }
    int sv[4]; int er_[4]; bool vr[4];
    for (int r = 0; r < 4; r++){
      int e = c0 + q*4 + r;
      vr[r] = (e < re);
      int ec = min(e, re-1);
      er_[r] = e;
      sv[r] = clampi(src_s[ec], 0, N_NODES-1);
    }
    for (int c = 0; c < 8; c++){
      floatx4 acc = {0.f,0.f,0.f,0.f};
      const unsigned short* bp = Wep + (size_t)(c*4)*512 + lane*8;
      for (int kk = 0; kk < 4; kk++){
        short8 bf = ld_frag16(bp + kk*512);
        acc = __builtin_amdgcn_mfma_f32_16x16x32_bf16(af[kk], bf, acc, 0, 0, 0);
      }
      float bias = biase[c*16 + l15];
      float qv = bf2f(q_b[(size_t)n*128 + c*16 + l15]);
      float t0[4];
      for (int r = 0; r < 4; r++){
        float kvv = bf2f(k_b[(size_t)sv[r]*128 + c*16 + l15]);
        t0[r] = siluf(acc[r] + bias) * qv * kvv;
      }
      for (int m = 1; m <= 8; m <<= 1)
        for (int r = 0; r < 4; r++) t0[r] += __shfl_xor(t0[r], m);
      if (l15 == 0){
        for (int r = 0; r < 4; r++)
          if (vr[r]) alpha_s[(size_t)er_[r]*8 + c] = t0[r];
      }
      for (int r = 0; r < 4; r++){
        if (vr[r]){
          float t = t0[r];
          float mn = fmaxf(m_run[c], t);
          z_run[c] = z_run[c]*__expf(m_run[c]-mn) + __expf(t-mn);
          m_run[c] = mn;
        }
      }
    }
  }
  // merge stats across the 4 lane-groups (butterfly leaves full result on all lanes)
  for (int h = 0; h < 8; h++){
    float mo = m_run[h], zo = z_run[h];
    for (int m = 16; m <= 32; m <<= 1){
      float m2 = __shfl_xor(mo, m), z2 = __shfl_xor(zo, m);
      float mn = fmaxf(mo, m2);
      zo = zo*__expf(mo-mn) + z2*__expf(m2-mn);
      mo = mn;
    }
    m_run[h] = mo; z_run[h] = zo;
  }
  if (lane == 0){
    for (int h = 0; h < 8; h++){
      stats_s[(size_t)n*16 + h]     = m_run[h];
      stats_s[(size_t)n*16 + 8 + h] = 1.f / (z_run[h] + 1e-16f);
    }
  }
}

// ---------------------------------------------------------------- pass C: messages + fused node reduction
__global__ void __launch_bounds__(256) k_msg(const float* s_in, const float* v_in,
                     const float* r_ij,
                     const float* ln_g, const float* ln_b,
                     const unsigned short* xv_b, const unsigned short* vt_b,
                     const unsigned short* Wep, const float* biase,
                     const int* row_start, const int* perm_s, const int* src_s,
                     const float* dird_s, const float* alpha_s, const float* stats_s,
                     float* out_s, float* out_v)
{
  int wid = threadIdx.x >> 6, lane = threadIdx.x & 63;
  int n = blockIdx.x*4 + wid;
  int l15 = lane & 15, q = lane >> 4;
  int rs = clampi(row_start[n], 0, N_EDGES);
  int re = clampi(row_start[n+1], rs, N_EDGES);

  float accS[2] = {0.f, 0.f};
  float accV[6] = {0.f,0.f,0.f,0.f,0.f,0.f};

  // distributed per-head softmax stats: lane h (h<8) owns head h (2 VGPRs)
  int lh = lane & 7;
  float mh = stats_s[(size_t)n*16 + lh];
  float zi = stats_s[(size_t)n*16 + 8 + lh];

  for (int c0 = rs; c0 < re; c0 += 16){
    int iA = min(c0 + l15, re-1);
    int pA = clampi(perm_s[iA], 0, N_EDGES-1);
    const float* ar = r_ij + (size_t)pA*128 + q*8;
    short8 af[4];
    for (int kk = 0; kk < 4; kk++){
      float4 a0 = *(const float4*)(ar + kk*32);
      float4 a1 = *(const float4*)(ar + kk*32 + 4);
      short8 f;
      f[0]=(short)f2bf(a0.x); f[1]=(short)f2bf(a0.y); f[2]=(short)f2bf(a0.z); f[3]=(short)f2bf(a0.w);
      f[4]=(short)f2bf(a1.x); f[5]=(short)f2bf(a1.y); f[6]=(short)f2bf(a1.z); f[7]=(short)f2bf(a1.w);
      af[kk] = f;
    }

    // per-edge metadata (sorted-order indexed: no perm indirection)
    int sv[4]; int er_[4]; bool vr[4]; float cc[4], dv0[4], dv1[4], dv2[4];
    for (int r = 0; r < 4; r++){
      int e = c0 + q*4 + r;
      vr[r] = (e < re);
      int ec = min(e, re-1);
      er_[r] = ec;
      sv[r] = clampi(src_s[ec], 0, N_NODES-1);
      float4 dd = *(const float4*)(dird_s + (size_t)ec*4);
      cc[r] = (vr[r] && dd.w < 5.0f) ? 0.5f*(__cosf(dd.w*0.6283185307179587f) + 1.f) : 0.f;
      dv0[r] = dd.x; dv1[r] = dd.y; dv2[r] = dd.z;
    }

    float at4[4] = {0.f,0.f,0.f,0.f};
    for (int c = 0; c < 24; c++){
      if (c % 3 == 0){
        int h = c / 3;
        float mhc = __shfl(mh, h);
        float zic = __shfl(zi, h);
        for (int r = 0; r < 4; r++)
          at4[r] = vr[r] ? __expf(alpha_s[(size_t)er_[r]*8 + h] - mhc) * zic : 0.f;
      }
      floatx4 acc = {0.f,0.f,0.f,0.f};
      const unsigned short* bp = Wep + (size_t)((8+c)*4)*512 + lane*8;
      for (int kk = 0; kk < 4; kk++){
        short8 bf = ld_frag16(bp + kk*512);
        acc = __builtin_amdgcn_mfma_f32_16x16x32_bf16(af[kk], bf, acc, 0, 0, 0);
      }
      float bias = biase[128 + c*16 + l15];
      float msg[4];
      for (int r = 0; r < 4; r++){
        unsigned int xv = *(const unsigned int*)(xv_b + (((size_t)sv[r]*384 + c*16 + l15) << 1));
        float xvf = bf2f((unsigned short)(xv & 0xffffu));
        float vvf = bf2f((unsigned short)(xv >> 16));
        msg[r] = (acc[r] + bias) * xvf * cc[r] + at4[r] * vvf;
      }
      if (c < 8){
        float s4 = msg[0]+msg[1]+msg[2]+msg[3];
        s4 += __shfl_xor(s4, 16); s4 += __shfl_xor(s4, 32);
        if (q == (c & 3)) accS[c >> 2] += s4;
      } else if (c < 16){
        int b = c - 8;
        float p0 = msg[0]*dv0[0] + msg[1]*dv0[1] + msg[2]*dv0[2] + msg[3]*dv0[3];
        float p1 = msg[0]*dv1[0] + msg[1]*dv1[1] + msg[2]*dv1[2] + msg[3]*dv1[3];
        float p2 = msg[0]*dv2[0] + msg[1]*dv2[1] + msg[2]*dv2[2] + msg[3]*dv2[3];
        p0 += __shfl_xor(p0, 16); p0 += __shfl_xor(p0, 32);
        p1 += __shfl_xor(p1, 16); p1 += __shfl_xor(p1, 32);
        p2 += __shfl_xor(p2, 16); p2 += __shfl_xor(p2, 32);
        if (q == (b & 3)){
          accV[(b >> 2)*3 + 0] += p0;
          accV[(b >> 2)*3 + 1] += p1;
          accV[(b >> 2)*3 + 2] += p2;
        }
      } else {
        int b = c - 16;
        float p0 = 0.f, p1 = 0.f, p2 = 0.f;
        for (int r = 0; r < 4; r++){
          uint2 vv = *(const uint2*)(vt_b + (((size_t)sv[r]*128 + b*16 + l15) << 2));
          p0 += msg[r] * bf2f((unsigned short)(vv.x & 0xffffu));
          p1 += msg[r] * bf2f((unsigned short)(vv.x >> 16));
          p2 += msg[r] * bf2f((unsigned short)(vv.y & 0xffffu));
        }
        p0 += __shfl_xor(p0, 16); p0 += __shfl_xor(p0, 32);
        p1 += __shfl_xor(p1, 16); p1 += __shfl_xor(p1, 32);
        p2 += __shfl_xor(p2, 16); p2 += __shfl_xor(p2, 32);
        if (q == (b & 3)){
          accV[(b >> 2)*3 + 0] += p0;
          accV[(b >> 2)*3 + 1] += p1;
          accV[(b >> 2)*3 + 2] += p2;
        }
      }
    }
  }

  // epilogue: recompute LN(s) in f32 and fuse s_out = LN(s) + su ; v_out = v + vu
  {
    int ch0 = q*16 + l15, ch1 = 64 + q*16 + l15;
    float x0 = s_in[(size_t)n*128 + ch0];
    float x1 = s_in[(size_t)n*128 + ch1];
    float sm = x0 + x1, ssq = x0*x0 + x1*x1;
    for (int m = 1; m <= 32; m <<= 1){ sm += __shfl_xor(sm, m); ssq += __shfl_xor(ssq, m); }
    float mean = sm * (1.f/128.f);
    float var = ssq * (1.f/128.f) - mean*mean;
    float rsv = rsqrtf(var + 1e-5f);
    float y0 = (x0-mean)*rsv*ln_g[ch0] + ln_b[ch0];
    float y1 = (x1-mean)*rsv*ln_g[ch1] + ln_b[ch1];
    out_s[(size_t)n*128 + ch0] = y0 + accS[0];
    out_s[(size_t)n*128 + ch1] = y1 + accS[1];
  }
  for (int t = 0; t < 6; t++){
    int b = (t/3)*4 + q;
    int a = t - (t/3)*3;
    int ch = b*16 + l15;
    size_t idx = ((size_t)n*3 + a)*128 + ch;
    out_v[idx] = v_in[idx] + accV[t];
  }
}

// ---------------------------------------------------------------- launch
extern "C" void kernel_launch(void* const* d_in, const int* in_sizes, int n_in,
                              void* d_out, int out_size, void* d_ws, size_t ws_size,
                              hipStream_t stream)
{
  const float* s_in   = (const float*)d_in[0];
  const float* v_in   = (const float*)d_in[1];
  const float* dir_ij = (const float*)d_in[2];
  const float* d_ij   = (const float*)d_in[3];
  const float* r_ij   = (const float*)d_in[4];
  const int*   ei     = (const int*)d_in[5];
  const float* ln_g   = (const float*)d_in[6];
  const float* ln_b   = (const float*)d_in[7];
  const float* Wq  = (const float*)d_in[8];
  const float* bq  = (const float*)d_in[9];
  const float* Wk  = (const float*)d_in[10];
  const float* bk  = (const float*)d_in[11];
  const float* Wg1 = (const float*)d_in[12];
  const float* bg1 = (const float*)d_in[13];
  const float* Wg2 = (const float*)d_in[14];
  const float* bg2 = (const float*)d_in[15];
  const float* Wv1 = (const float*)d_in[16];
  const float* bv1 = (const float*)d_in[17];
  const float* Wv2 = (const float*)d_in[18];
  const float* bv2 = (const float*)d_in[19];
  const float* Wre = (const float*)d_in[20];
  const float* bre = (const float*)d_in[21];
  const float* Wra = (const float*)d_in[22];
  const float* bra = (const float*)d_in[23];

  float* out_s = (float*)d_out;
  float* out_v = out_s + (size_t)N_NODES*128;
  float* out_r = out_v + (size_t)N_NODES*384;

  char* w = (char*)d_ws;
  size_t off = 0;
  auto alloc = [&](size_t bytes) -> void* {
    void* p = w + off;
    off = (off + bytes + 255) & ~(size_t)255;
    return p;
  };
  // region 0: h1|h2 during ngemm1/2, then alpha_s (same 10.24 MB)
  char* reg0 = (char*)alloc((size_t)N_EDGES*8*4);
  unsigned short* h1_b  = (unsigned short*)reg0;
  unsigned short* h2_b  = (unsigned short*)(reg0 + (size_t)N_NODES*128*2);
  float* alpha_s        = (float*)reg0;
  // region 1: xv (x3|val interleaved); its first 5.12 MB doubles as s2b before ngemm2
  unsigned short* xv_b  = (unsigned short*)alloc((size_t)N_NODES*384*2*2);
  unsigned short* s2b   = xv_b;
  unsigned short* q_b   = (unsigned short*)alloc((size_t)N_NODES*128*2);
  unsigned short* k_b   = (unsigned short*)alloc((size_t)N_NODES*128*2);
  unsigned short* vt_b  = (unsigned short*)alloc((size_t)N_NODES*128*4*2);
  float* dird_s  = (float*)alloc((size_t)N_EDGES*4*4);
  float* stats_s = (float*)alloc((size_t)N_NODES*16*4);
  unsigned short* B1p   = (unsigned short*)alloc(65536*2);
  unsigned short* Wg2p  = (unsigned short*)alloc(49152*2);
  unsigned short* Wv2p  = (unsigned short*)alloc(49152*2);
  unsigned short* Wep   = (unsigned short*)alloc(65536*2);
  float* bias1  = (float*)alloc(512*4);
  float* biasg2 = (float*)alloc(384*4);
  float* biasv2 = (float*)alloc(384*4);
  float* biase  = (float*)alloc(512*4);
  int* hist      = (int*)alloc((size_t)N_NODES*4);
  int* row_start = (int*)alloc((size_t)(N_NODES+1)*4);
  int* cursor    = (int*)alloc((size_t)N_NODES*4);
  int* perm_s    = (int*)alloc((size_t)N_EDGES*4);
  int* src_s     = (int*)alloc((size_t)N_EDGES*4);

  k_pack<<<896, 256, 0, stream>>>(Wq, Wk, Wg1, Wv1, Wg2, Wv2, Wre, Wra,
                                  bq, bk, bg1, bv1, bg2, bv2, bre, bra,
                                  B1p, Wg2p, Wv2p, Wep,
                                  bias1, biasg2, biasv2, biase, hist);
  k_ln<<<5000, 256, 0, stream>>>(s_in, v_in, ln_g, ln_b, s2b, vt_b);
  k_hist<<<1250, 256, 0, stream>>>(ei, hist);
  k_scan<<<1, 1024, 0, stream>>>(hist, row_start, cursor);
  k_scatter<<<1250, 256, 0, stream>>>(ei, dir_ij, d_ij, cursor, perm_s, src_s, dird_s);
  k_ngemm1<<<313, 256, 0, stream>>>(s2b, B1p, bias1, q_b, k_b, h1_b, h2_b);
  k_ngemm2<<<313, 256, 0, stream>>>(h1_b, h2_b, Wg2p, Wv2p, biasg2, biasv2, xv_b);
  k_alpha<<<5000, 256, 0, stream>>>(r_ij, q_b, k_b, Wep, biase, row_start, perm_s, src_s,
                                    alpha_s, stats_s, out_r);
  k_msg<<<5000, 256, 0, stream>>>(s_in, v_in, r_ij, ln_g, ln_b,
                                  xv_b, vt_b, Wep, biase,
                                  row_start, perm_s, src_s, dird_s, alpha_s, stats_s,
                                  out_s, out_v);
}